// Round 2
// baseline (1046.334 us; speedup 1.0000x reference)
//
#include <hip/hip_runtime.h>
#include <stdint.h>

typedef unsigned int u32;
typedef unsigned long long u64;

#define DEVI __device__ __forceinline__

constexpr int PRE_K = 1000;
constexpr int CAP = 8192;

// workspace layout (bytes)
constexpr size_t WT_OFF   = 0;          // 128*9*128 f32 = 589824
constexpr size_t HIST_OFF = 589824;     // 2*4096 u32 = 32768
constexpr size_t CNT_OFF  = 622592;     // 2 u32
constexpr size_t CUT_OFF  = 622656;     // 2 u32
constexpr size_t CAND_OFF = 622848;     // 2*8192 u64 = 131072 -> 753920
constexpr size_t TB_OFF   = 753920;     // 2*1000*4 f32 = 32000 -> 785920
constexpr size_t SCS_OFF  = 785920;     // 2*1000 f32 = 8000 -> 793920
constexpr size_t MASK_OFF = 793984;     // 2*1024*16 u64 = 262144 -> 1056128

constexpr size_t KB_OFF = 655360;   // kept_boxes offset in d_out (floats)
constexpr size_t KS_OFF = 657408;   // kept_scores offset in d_out (floats)

DEVI u32 fkey(float f) {
  u32 u = __float_as_uint(f);
  return (u & 0x80000000u) ? ~u : (u | 0x80000000u);
}

DEVI u64 shfl64(u64 v, int src) {
  int lo = __shfl((int)(u32)v, src, 64);
  int hi = __shfl((int)(u32)(v >> 32), src, 64);
  return ((u64)(u32)hi << 32) | (u64)(u32)lo;
}

// ---- W_conv (co,ci,3,3) -> wt[ci][tap][co] ----
__global__ void wtransk(const float* __restrict__ wc, float* __restrict__ wt) {
  int e = blockIdx.x * 256 + threadIdx.x;      // < 147456
  int co = e & 127;
  int rest = e >> 7;                            // ci*9 + t
  int t = rest % 9;
  int ci = rest / 9;
  wt[e] = wc[(co * 128 + ci) * 9 + t];
}

// ---- fused conv3x3 + bias + relu + heads + box decode ----
__global__ __launch_bounds__(256) void convk(
    const float* __restrict__ x, const float* __restrict__ wt,
    const float* __restrict__ bconv,
    const float* __restrict__ woff, const float* __restrict__ boff,
    const float* __restrict__ wlog, const float* __restrict__ blog,
    const int* __restrict__ ihp, const int* __restrict__ iwp,
    float* __restrict__ out)
{
  __shared__ float xs[8][18][12];
  __shared__ float wsh[8][9][128];

  int tid = threadIdx.x;
  int bw = blockIdx.x, bh = blockIdx.y, n = blockIdx.z;
  int gh0 = bh * 16, gw0 = bw * 8;
  int pg = tid & 31, cog = tid >> 5;
  int qr = (pg >> 2) << 1;      // 0,2,...,14
  int qc = (pg & 3) << 1;       // 0,2,4,6
  int co0 = cog << 4;

  float acc[4][16];
#pragma unroll
  for (int p = 0; p < 4; ++p)
#pragma unroll
    for (int o = 0; o < 16; ++o) acc[p][o] = 0.f;

#pragma unroll 1
  for (int ci0 = 0; ci0 < 128; ci0 += 8) {
    // stage x halo tile: 8ci x 18 x 10
    for (int e = tid; e < 8 * 18 * 10; e += 256) {
      int ci = e / 180;
      int rr = (e / 10) % 18;
      int c = e % 10;
      int gh = gh0 + rr - 1, gw = gw0 + c - 1;
      float v = 0.f;
      if ((unsigned)gh < 256u && (unsigned)gw < 256u)
        v = x[(((size_t)n * 128 + ci0 + ci) * 256 + gh) * 256 + gw];
      xs[ci][rr][c] = v;
    }
    // stage weights (contiguous copy)
    {
      const float* src = wt + (size_t)ci0 * 9 * 128;
      float* dst = &wsh[0][0][0];
      for (int e = tid; e < 8 * 9 * 128; e += 256) dst[e] = src[e];
    }
    __syncthreads();

#pragma unroll 1
    for (int ci = 0; ci < 8; ++ci) {
      float xp[4][4];
#pragma unroll
      for (int r = 0; r < 4; ++r)
#pragma unroll
        for (int c = 0; c < 4; ++c) xp[r][c] = xs[ci][qr + r][qc + c];
#pragma unroll
      for (int t = 0; t < 9; ++t) {
        const int ty = t / 3, tx = t - ty * 3;
        const float4* wp = (const float4*)&wsh[ci][t][co0];
        float4 wa = wp[0], wb = wp[1], wc4 = wp[2], wd = wp[3];
        float wreg[16] = {wa.x, wa.y, wa.z, wa.w, wb.x, wb.y, wb.z, wb.w,
                          wc4.x, wc4.y, wc4.z, wc4.w, wd.x, wd.y, wd.z, wd.w};
#pragma unroll
        for (int p = 0; p < 4; ++p) {
          float xv = xp[(p >> 1) + ty][(p & 1) + tx];
#pragma unroll
          for (int o = 0; o < 16; ++o) acc[p][o] = fmaf(xv, wreg[o], acc[p][o]);
        }
      }
    }
    __syncthreads();
  }

  // bias + relu
#pragma unroll
  for (int o = 0; o < 16; ++o) {
    float b = bconv[co0 + o];
#pragma unroll
    for (int p = 0; p < 4; ++p) acc[p][o] = fmaxf(acc[p][o] + b, 0.f);
  }

  // heads: 19 outputs per pixel, deterministic LDS reduce (reuse wsh)
  float* hb = &wsh[0][0][0];   // 128px * 20 floats
  for (int e = tid; e < 128 * 20; e += 256) hb[e] = 0.f;
  __syncthreads();

  int pxl[4];
#pragma unroll
  for (int p = 0; p < 4; ++p) pxl[p] = (qr + (p >> 1)) * 8 + (qc + (p & 1));

#pragma unroll 1
  for (int o = 0; o < 19; ++o) {
    const float* wh = (o < 18) ? (woff + o * 128) : wlog;
    float wv[16];
#pragma unroll
    for (int k = 0; k < 16; ++k) wv[k] = wh[co0 + k];
    float part[4];
#pragma unroll
    for (int p = 0; p < 4; ++p) {
      float s = 0.f;
#pragma unroll
      for (int k = 0; k < 16; ++k) s = fmaf(acc[p][k], wv[k], s);
      part[p] = s;
    }
#pragma unroll 1
    for (int g = 0; g < 8; ++g) {
      if (cog == g) {
#pragma unroll
        for (int p = 0; p < 4; ++p) hb[pxl[p] * 20 + o] += part[p];
      }
      __syncthreads();
    }
  }

  if (tid < 128) {
    int lh = tid >> 3, lw = tid & 7;
    int gh = gh0 + lh, gw = gw0 + lw;
    int ihv = ihp[0], iwv = iwp[0];
    float sc = hb[tid * 20 + 18] + blog[0];
    // xs_lin uses linspace(0, image_h-1, Wf) indexed by w; ys_lin uses image_w, indexed by h
    float xv = (float)((double)gw * ((double)(ihv - 1) / 255.0));
    float yv = (float)((double)gh * ((double)(iwv - 1) / 255.0));
    float scale = (float)iwv / 256.0f;
    float mnx = __builtin_inff(), mny = __builtin_inff();
    float mxx = -__builtin_inff(), mxy = -__builtin_inff();
#pragma unroll
    for (int p = 0; p < 9; ++p) {
      float ox = expf((hb[tid * 20 + 2 * p] + boff[2 * p]) * scale) - 1.f + xv;
      float oy = expf((hb[tid * 20 + 2 * p + 1] + boff[2 * p + 1]) * scale) - 1.f + yv;
      float cx = fminf(fmaxf(ox, 0.f), (float)(iwv - 1));
      float cy = fminf(fmaxf(oy, 0.f), (float)(ihv - 1));
      mnx = fminf(mnx, cx); mxx = fmaxf(mxx, cx);
      mny = fminf(mny, cy); mxy = fmaxf(mxy, cy);
    }
    size_t pix = (size_t)n * 65536 + (size_t)gh * 256 + gw;
    float* rec = out + pix * 5;
    rec[0] = sc; rec[1] = mnx; rec[2] = mny; rec[3] = mxx; rec[4] = mxy;
  }
}

// ---- histogram of 12-bit key prefixes ----
__global__ void histk(const float* __restrict__ out, u32* __restrict__ hist) {
  int e = blockIdx.x * 256 + threadIdx.x;   // < 131072
  int n = e >> 16;
  int pix = e & 65535;
  float sc = out[((size_t)n * 65536 + pix) * 5];
  atomicAdd(&hist[n * 4096 + (fkey(sc) >> 20)], 1u);
}

// ---- find cutoff bin (rank PRE_K) ----
__global__ __launch_bounds__(256) void cutoffk(const u32* __restrict__ hist, u32* __restrict__ cut) {
  int n = blockIdx.x;
  const u32* h = hist + n * 4096;
  __shared__ u32 pre[256];
  int t = threadIdx.x;
  u32 s0 = 0;
  for (int k = 0; k < 16; ++k) s0 += h[4095 - (t * 16 + k)];
  pre[t] = s0;
  __syncthreads();
  for (int off = 1; off < 256; off <<= 1) {
    u32 add = (t >= off) ? pre[t - off] : 0u;
    __syncthreads();
    pre[t] += add;
    __syncthreads();
  }
  u32 incl = pre[t];
  u32 excl = incl - s0;
  if (incl >= (u32)PRE_K && excl < (u32)PRE_K) {
    u32 cum = excl;
    for (int k = 0; k < 16; ++k) {
      int b = 4095 - (t * 16 + k);
      cum += h[b];
      if (cum >= (u32)PRE_K) { cut[n] = ((u32)b) << 20; break; }
    }
  }
}

// ---- collect candidates >= cutoff ----
__global__ void collectk(const float* __restrict__ out, const u32* __restrict__ cut,
                         u32* __restrict__ cnt, u64* __restrict__ cand) {
  int e = blockIdx.x * 256 + threadIdx.x;
  int n = e >> 16;
  u32 pix = e & 65535;
  float sc = out[((size_t)n * 65536 + pix) * 5];
  u32 key = fkey(sc);
  if (key >= cut[n]) {
    u32 pos = atomicAdd(&cnt[n], 1u);
    if (pos < (u32)CAP)
      cand[(size_t)n * CAP + pos] = ((u64)key << 32) | (u64)(0xFFFFFFFFu - pix);
  }
}

// ---- bitonic sort (desc) of 8192 composites; emit top-1000 ----
__global__ __launch_bounds__(1024) void sortk(const u64* __restrict__ cand, const u32* __restrict__ cnt,
                                              const float* __restrict__ out,
                                              float* __restrict__ tb, float* __restrict__ scs) {
  int n = blockIdx.x;
  int t = threadIdx.x;
  __shared__ u64 d[CAP];
  u32 m = cnt[n]; if (m > (u32)CAP) m = CAP;
  for (int i = t; i < CAP; i += 1024) d[i] = (i < (int)m) ? cand[(size_t)n * CAP + i] : 0ull;
  __syncthreads();
  for (int k = 2; k <= CAP; k <<= 1) {
    for (int j = k >> 1; j > 0; j >>= 1) {
      for (int i = t; i < CAP; i += 1024) {
        int l = i ^ j;
        if (l > i) {
          u64 a = d[i], b = d[l];
          bool up = (i & k) == 0;
          bool sw = up ? (a < b) : (a > b);
          if (sw) { d[i] = b; d[l] = a; }
        }
      }
      __syncthreads();
    }
  }
  if (t < PRE_K) {
    u64 v = d[t];
    u32 pix = 0xFFFFFFFFu - (u32)(v & 0xFFFFFFFFull);
    const float* rec = out + ((size_t)n * 65536 + pix) * 5;
    float sc = rec[0];
    float b0 = rec[1], b1 = rec[2], b2 = rec[3], b3 = rec[4];
    bool valid = ((b2 - b0) >= 0.f) && ((b3 - b1) >= 0.f);
    scs[n * PRE_K + t] = valid ? sc : -__builtin_inff();
    float* tbp = tb + ((size_t)n * PRE_K + t) * 4;
    tbp[0] = b0; tbp[1] = b1; tbp[2] = b2; tbp[3] = b3;
  }
}

// ---- pairwise IoU suppression bitmasks (1024 rows/image; rows >=1000 zero) ----
__global__ __launch_bounds__(1024) void maskk(const float* __restrict__ tb, u64* __restrict__ maskw) {
  int n = blockIdx.x;
  int t = threadIdx.x;
  __shared__ float bx[PRE_K][4];
  for (int e = t; e < PRE_K * 4; e += 1024) ((float*)bx)[e] = tb[(size_t)n * PRE_K * 4 + e];
  __syncthreads();
  float x1 = 0.f, y1 = 0.f, x2 = 0.f, y2 = 0.f, ai = 0.f;
  if (t < PRE_K) {
    x1 = bx[t][0]; y1 = bx[t][1]; x2 = bx[t][2]; y2 = bx[t][3];
    ai = (x2 - x1) * (y2 - y1);
  }
  for (int w = 0; w < 16; ++w) {
    u64 accm = 0;
    if (t < PRE_K) {
      int j0 = max(t + 1, w * 64), j1 = min(PRE_K, (w + 1) * 64);
      for (int j = j0; j < j1; ++j) {
        float u1 = bx[j][0], v1 = bx[j][1], u2 = bx[j][2], v2 = bx[j][3];
        float aj = (u2 - u1) * (v2 - v1);
        float iw = fminf(x2, u2) - fmaxf(x1, u1); iw = fmaxf(iw, 0.f);
        float ih = fminf(y2, v2) - fmaxf(y1, v1); ih = fmaxf(ih, 0.f);
        float inter = iw * ih;
        float iou = inter / (ai + aj - inter + 1e-9f);
        if (iou > 0.7f) accm |= (1ull << (j & 63));
      }
    }
    maskw[((size_t)n * 1024 + t) * 16 + w] = accm;
  }
}

// ---- serial greedy scan (reg-prefetch from global) + stable partition ----
__global__ __launch_bounds__(64) void finalk(const u64* __restrict__ maskw,
                                             const float* __restrict__ scs,
                                             const float* __restrict__ tb,
                                             float* __restrict__ out) {
  int n = blockIdx.x;
  int lane = threadIdx.x;
  __shared__ float lsc[1024];
  __shared__ unsigned short ordA[1024];
  __shared__ unsigned short ordB[1024];
  for (int e = lane; e < 1024; e += 64)
    lsc[e] = (e < PRE_K) ? scs[n * PRE_K + e] : -__builtin_inff();
  __syncthreads();

  // fold validity into initial suppression mask: lane c (<16) owns word c
  u64 sup = 0;
#pragma unroll
  for (int c = 0; c < 16; ++c) {
    u64 b = __ballot(!(lsc[c * 64 + lane] > -__builtin_inff()));
    if (lane == c) sup = b;
  }

  const u64* gm = maskw + (size_t)n * 1024 * 16;
  u64 pre[16];
#pragma unroll
  for (int d = 0; d < 16; ++d)
    pre[d] = (lane < 16) ? gm[d * 16 + lane] : 0ull;

  // serial greedy scan: no memory op on the dependency chain
  for (int i0 = 0; i0 < 1024; i0 += 16) {
#pragma unroll
    for (int d = 0; d < 16; ++d) {
      int i = i0 + d;
      u64 mi = pre[d];
      int nx = i + 16;
      pre[d] = (nx < 1024 && lane < 16) ? gm[(size_t)nx * 16 + lane] : 0ull;
      int w = i >> 6;
      u64 sw = shfl64(sup, w);
      bool supbit = (sw >> (i & 63)) & 1ull;
      if (!supbit) sup |= mi;
    }
  }

  // stable partition: survivors (rank order) then rest (index order)
  u64 ltm = (1ull << lane) - 1ull;
  u32 baseA = 0, baseB = 0;
  for (int c = 0; c < 16; ++c) {
    int i = c * 64 + lane;
    u64 sw = shfl64(sup, c);
    bool bit = (sw >> lane) & 1ull;
    bool vi = i < PRE_K;
    bool sf = vi && !bit && (lsc[vi ? i : 0] > -__builtin_inff());
    u64 mA = __ballot(sf);
    u64 mB = __ballot(vi && !sf);
    if (sf) ordA[baseA + __popcll(mA & ltm)] = (unsigned short)i;
    else if (vi) ordB[baseB + __popcll(mB & ltm)] = (unsigned short)i;
    baseA += (u32)__popcll(mA);
    baseB += (u32)__popcll(mB);
  }
  __syncthreads();

  for (int r = 0; r < 4; ++r) {
    int k = r * 64 + lane;   // 0..255
    int fi; float v;
    if (k < (int)baseA) { fi = ordA[k]; v = lsc[fi]; }
    else { fi = ordB[k - baseA]; v = -__builtin_inff(); }
    const float* bp = tb + ((size_t)n * PRE_K + fi) * 4;
    float* kb = out + KB_OFF + ((size_t)n * 256 + k) * 4;
    kb[0] = bp[0]; kb[1] = bp[1]; kb[2] = bp[2]; kb[3] = bp[3];
    out[KS_OFF + (size_t)n * 256 + k] = v;
  }
}

extern "C" void kernel_launch(void* const* d_in, const int* in_sizes, int n_in,
                              void* d_out, int out_size, void* d_ws, size_t ws_size,
                              hipStream_t stream) {
  const float* x     = (const float*)d_in[0];
  const float* wc    = (const float*)d_in[1];
  const float* bconv = (const float*)d_in[2];
  const float* woff  = (const float*)d_in[3];
  const float* boff  = (const float*)d_in[4];
  const float* wlog  = (const float*)d_in[5];
  const float* blog  = (const float*)d_in[6];
  const int* ihp     = (const int*)d_in[7];
  const int* iwp     = (const int*)d_in[8];
  float* out = (float*)d_out;
  char* ws = (char*)d_ws;

  float* wt   = (float*)(ws + WT_OFF);
  u32* hist   = (u32*)(ws + HIST_OFF);
  u32* cnt    = (u32*)(ws + CNT_OFF);
  u32* cut    = (u32*)(ws + CUT_OFF);
  u64* cand   = (u64*)(ws + CAND_OFF);
  float* tb   = (float*)(ws + TB_OFF);
  float* scs  = (float*)(ws + SCS_OFF);
  u64* maskw  = (u64*)(ws + MASK_OFF);

  hipLaunchKernelGGL(wtransk, dim3(576), dim3(256), 0, stream, wc, wt);
  hipLaunchKernelGGL(convk, dim3(32, 16, 2), dim3(256), 0, stream,
                     x, wt, bconv, woff, boff, wlog, blog, ihp, iwp, out);
  hipMemsetAsync(ws + HIST_OFF, 0, (CAND_OFF - HIST_OFF), stream);
  hipLaunchKernelGGL(histk, dim3(512), dim3(256), 0, stream, out, hist);
  hipLaunchKernelGGL(cutoffk, dim3(2), dim3(256), 0, stream, hist, cut);
  hipLaunchKernelGGL(collectk, dim3(512), dim3(256), 0, stream, out, cut, cnt, cand);
  hipLaunchKernelGGL(sortk, dim3(2), dim3(1024), 0, stream, cand, cnt, out, tb, scs);
  hipLaunchKernelGGL(maskk, dim3(2), dim3(1024), 0, stream, tb, maskw);
  hipLaunchKernelGGL(finalk, dim3(2), dim3(64), 0, stream, maskw, scs, tb, out);
}

// Round 3
// 822.920 us; speedup vs baseline: 1.2715x; 1.2715x over previous
//
#include <hip/hip_runtime.h>
#include <stdint.h>

typedef unsigned int u32;
typedef unsigned long long u64;

#define DEVI __device__ __forceinline__

constexpr int PRE_K = 1000;
constexpr int CAP = 8192;

// workspace layout (bytes)
constexpr size_t WT_OFF   = 0;          // 128*9*128 f32 = 589824
constexpr size_t HIST_OFF = 589824;     // 2*4096 u32 = 32768
constexpr size_t CNT_OFF  = 622592;     // 2 u32
constexpr size_t CUT_OFF  = 622656;     // 2 u32
constexpr size_t CAND_OFF = 622848;     // 2*8192 u64 = 131072 -> 753920
constexpr size_t TB_OFF   = 753920;     // 2*1000*4 f32 = 32000 -> 785920
constexpr size_t SCS_OFF  = 785920;     // 2*1000 f32 = 8000 -> 793920
constexpr size_t MASK_OFF = 793984;     // 2*1024*16 u64 = 262144 -> 1056128
constexpr size_t SCARR_OFF= 1056128;    // 2*65536 f32 = 524288 -> 1580416
constexpr size_t WS_NEED  = 1580416;

constexpr size_t KB_OFF = 655360;   // kept_boxes offset in d_out (floats)
constexpr size_t KS_OFF = 657408;   // kept_scores offset in d_out (floats)

DEVI u32 fkey(float f) {
  u32 u = __float_as_uint(f);
  return (u & 0x80000000u) ? ~u : (u | 0x80000000u);
}

DEVI u64 shfl64(u64 v, int src) {
  int lo = __shfl((int)(u32)v, src, 64);
  int hi = __shfl((int)(u32)(v >> 32), src, 64);
  return ((u64)(u32)hi << 32) | (u64)(u32)lo;
}

// ---- W_conv (co,ci,3,3) -> wt[ci][tap][co] ----
__global__ void wtransk(const float* __restrict__ wc, float* __restrict__ wt) {
  int e = blockIdx.x * 256 + threadIdx.x;      // < 147456
  int co = e & 127;
  int rest = e >> 7;                            // ci*9 + t
  int t = rest % 9;
  int ci = rest / 9;
  wt[e] = wc[(co * 128 + ci) * 9 + t];
}

// ---- fused conv3x3 + bias + relu + heads + box decode + score hist ----
__global__ __launch_bounds__(256) void convk(
    const float* __restrict__ x, const float* __restrict__ wt,
    const float* __restrict__ bconv,
    const float* __restrict__ woff, const float* __restrict__ boff,
    const float* __restrict__ wlog, const float* __restrict__ blog,
    const int* __restrict__ ihp, const int* __restrict__ iwp,
    float* __restrict__ out, u32* __restrict__ hist, float* __restrict__ scarr)
{
  __shared__ float xs[4][18][12];
  __shared__ float wsh[4][9][128];

  int tid = threadIdx.x;
  int bw = blockIdx.x, bh = blockIdx.y, n = blockIdx.z;
  int gh0 = bh * 16, gw0 = bw * 8;
  int pg = tid & 31, cog = tid >> 5;
  int qr = (pg >> 2) << 1;      // 0,2,...,14
  int qc = (pg & 3) << 1;       // 0,2,4,6
  int co0 = cog << 4;

  float acc[4][16];
#pragma unroll
  for (int p = 0; p < 4; ++p)
#pragma unroll
    for (int o = 0; o < 16; ++o) acc[p][o] = 0.f;

#pragma unroll 1
  for (int ci0 = 0; ci0 < 128; ci0 += 4) {
    // stage x halo tile: 4ci x 18 x 10
    for (int e = tid; e < 4 * 18 * 10; e += 256) {
      int ci = e / 180;
      int rr = (e / 10) % 18;
      int c = e % 10;
      int gh = gh0 + rr - 1, gw = gw0 + c - 1;
      float v = 0.f;
      if ((unsigned)gh < 256u && (unsigned)gw < 256u)
        v = x[(((size_t)n * 128 + ci0 + ci) * 256 + gh) * 256 + gw];
      xs[ci][rr][c] = v;
    }
    // stage weights (contiguous copy)
    {
      const float* src = wt + (size_t)ci0 * 9 * 128;
      float* dst = &wsh[0][0][0];
      for (int e = tid; e < 4 * 9 * 128; e += 256) dst[e] = src[e];
    }
    __syncthreads();

#pragma unroll 1
    for (int ci = 0; ci < 4; ++ci) {
      float xp[4][4];
#pragma unroll
      for (int r = 0; r < 4; ++r)
#pragma unroll
        for (int c = 0; c < 4; ++c) xp[r][c] = xs[ci][qr + r][qc + c];
#pragma unroll
      for (int t = 0; t < 9; ++t) {
        const int ty = t / 3, tx = t - ty * 3;
        const float4* wp = (const float4*)&wsh[ci][t][co0];
        float4 wa = wp[0], wb = wp[1], wc4 = wp[2], wd = wp[3];
        float wreg[16] = {wa.x, wa.y, wa.z, wa.w, wb.x, wb.y, wb.z, wb.w,
                          wc4.x, wc4.y, wc4.z, wc4.w, wd.x, wd.y, wd.z, wd.w};
#pragma unroll
        for (int p = 0; p < 4; ++p) {
          float xv = xp[(p >> 1) + ty][(p & 1) + tx];
#pragma unroll
          for (int o = 0; o < 16; ++o) acc[p][o] = fmaf(xv, wreg[o], acc[p][o]);
        }
      }
    }
    __syncthreads();
  }

  // bias + relu
#pragma unroll
  for (int o = 0; o < 16; ++o) {
    float b = bconv[co0 + o];
#pragma unroll
    for (int p = 0; p < 4; ++p) acc[p][o] = fmaxf(acc[p][o] + b, 0.f);
  }

  // heads: 19 outputs per pixel, deterministic LDS reduce (reuse wsh)
  float* hb = &wsh[0][0][0];   // 128px * 20 floats (2560 <= 4608)
  for (int e = tid; e < 128 * 20; e += 256) hb[e] = 0.f;
  __syncthreads();

  int pxl[4];
#pragma unroll
  for (int p = 0; p < 4; ++p) pxl[p] = (qr + (p >> 1)) * 8 + (qc + (p & 1));

#pragma unroll 1
  for (int o = 0; o < 19; ++o) {
    const float* wh = (o < 18) ? (woff + o * 128) : wlog;
    float wv[16];
#pragma unroll
    for (int k = 0; k < 16; ++k) wv[k] = wh[co0 + k];
    float part[4];
#pragma unroll
    for (int p = 0; p < 4; ++p) {
      float s = 0.f;
#pragma unroll
      for (int k = 0; k < 16; ++k) s = fmaf(acc[p][k], wv[k], s);
      part[p] = s;
    }
#pragma unroll 1
    for (int g = 0; g < 8; ++g) {
      if (cog == g) {
#pragma unroll
        for (int p = 0; p < 4; ++p) hb[pxl[p] * 20 + o] += part[p];
      }
      __syncthreads();
    }
  }

  if (tid < 128) {
    int lh = tid >> 3, lw = tid & 7;
    int gh = gh0 + lh, gw = gw0 + lw;
    int ihv = ihp[0], iwv = iwp[0];
    float sc = hb[tid * 20 + 18] + blog[0];
    // xs_lin uses linspace(0, image_h-1, Wf) indexed by w; ys_lin uses image_w, indexed by h
    float xv = (float)((double)gw * ((double)(ihv - 1) / 255.0));
    float yv = (float)((double)gh * ((double)(iwv - 1) / 255.0));
    float scale = (float)iwv / 256.0f;
    float mnx = __builtin_inff(), mny = __builtin_inff();
    float mxx = -__builtin_inff(), mxy = -__builtin_inff();
#pragma unroll
    for (int p = 0; p < 9; ++p) {
      float ox = expf((hb[tid * 20 + 2 * p] + boff[2 * p]) * scale) - 1.f + xv;
      float oy = expf((hb[tid * 20 + 2 * p + 1] + boff[2 * p + 1]) * scale) - 1.f + yv;
      float cx = fminf(fmaxf(ox, 0.f), (float)(iwv - 1));
      float cy = fminf(fmaxf(oy, 0.f), (float)(ihv - 1));
      mnx = fminf(mnx, cx); mxx = fmaxf(mxx, cx);
      mny = fminf(mny, cy); mxy = fmaxf(mxy, cy);
    }
    size_t pix = (size_t)n * 65536 + (size_t)gh * 256 + gw;
    float* rec = out + pix * 5;
    rec[0] = sc; rec[1] = mnx; rec[2] = mny; rec[3] = mxx; rec[4] = mxy;
    if (scarr) scarr[pix] = sc;
    atomicAdd(&hist[n * 4096 + (fkey(sc) >> 20)], 1u);
  }
}

// ---- find cutoff bin (rank PRE_K) ----
__global__ __launch_bounds__(256) void cutoffk(const u32* __restrict__ hist, u32* __restrict__ cut) {
  int n = blockIdx.x;
  const u32* h = hist + n * 4096;
  __shared__ u32 pre[256];
  int t = threadIdx.x;
  u32 s0 = 0;
  for (int k = 0; k < 16; ++k) s0 += h[4095 - (t * 16 + k)];
  pre[t] = s0;
  __syncthreads();
  for (int off = 1; off < 256; off <<= 1) {
    u32 add = (t >= off) ? pre[t - off] : 0u;
    __syncthreads();
    pre[t] += add;
    __syncthreads();
  }
  u32 incl = pre[t];
  u32 excl = incl - s0;
  if (incl >= (u32)PRE_K && excl < (u32)PRE_K) {
    u32 cum = excl;
    for (int k = 0; k < 16; ++k) {
      int b = 4095 - (t * 16 + k);
      cum += h[b];
      if (cum >= (u32)PRE_K) { cut[n] = ((u32)b) << 20; break; }
    }
  }
}

// ---- collect candidates >= cutoff (coalesced via scarr when available) ----
__global__ void collectk(const float* __restrict__ out, const float* __restrict__ scarr,
                         const u32* __restrict__ cut,
                         u32* __restrict__ cnt, u64* __restrict__ cand) {
  int e = blockIdx.x * 256 + threadIdx.x;
  int n = e >> 16;
  u32 pix = e & 65535;
  float sc = scarr ? scarr[e] : out[((size_t)n * 65536 + pix) * 5];
  u32 key = fkey(sc);
  if (key >= cut[n]) {
    u32 pos = atomicAdd(&cnt[n], 1u);
    if (pos < (u32)CAP)
      cand[(size_t)n * CAP + pos] = ((u64)key << 32) | (u64)(0xFFFFFFFFu - pix);
  }
}

// ---- O(m^2) rank selection of top-1000 (order-invariant, exact ties by idx) ----
__global__ __launch_bounds__(1024) void ranksel(const u64* __restrict__ cand, const u32* __restrict__ cnt,
                                                const float* __restrict__ out,
                                                float* __restrict__ tb, float* __restrict__ scs) {
  int n = blockIdx.x;
  int t = threadIdx.x;
  __shared__ u64 d[CAP];
  u32 m = cnt[n]; if (m > (u32)CAP) m = CAP;
  for (int i = t; i < (int)m; i += 1024) d[i] = cand[(size_t)n * CAP + i];
  __syncthreads();
  for (int i = t; i < (int)m; i += 1024) {
    u64 ki = d[i];
    u32 r = 0;
    for (u32 j = 0; j < m; ++j) r += (d[j] > ki) ? 1u : 0u;
    if (r < (u32)PRE_K) {
      u32 pix = 0xFFFFFFFFu - (u32)(ki & 0xFFFFFFFFull);
      const float* rec = out + ((size_t)n * 65536 + pix) * 5;
      float sc = rec[0];
      float b0 = rec[1], b1 = rec[2], b2 = rec[3], b3 = rec[4];
      bool valid = ((b2 - b0) >= 0.f) && ((b3 - b1) >= 0.f);
      scs[n * PRE_K + r] = valid ? sc : -__builtin_inff();
      float* tbp = tb + ((size_t)n * PRE_K + r) * 4;
      tbp[0] = b0; tbp[1] = b1; tbp[2] = b2; tbp[3] = b3;
    }
  }
}

// ---- pairwise IoU suppression bitmasks; grid (colchunk=16, n=2) ----
__global__ __launch_bounds__(1024) void maskk(const float* __restrict__ tb, u64* __restrict__ maskw) {
  int c = blockIdx.x;
  int n = blockIdx.y;
  int t = threadIdx.x;
  __shared__ float bx[PRE_K][4];
  for (int e = t; e < PRE_K * 4; e += 1024) ((float*)bx)[e] = tb[(size_t)n * PRE_K * 4 + e];
  __syncthreads();
  u64 accm = 0;
  if (t < PRE_K) {
    float x1 = bx[t][0], y1 = bx[t][1], x2 = bx[t][2], y2 = bx[t][3];
    float ai = (x2 - x1) * (y2 - y1);
    int j0 = max(t + 1, c * 64), j1 = min(PRE_K, c * 64 + 64);
    for (int j = j0; j < j1; ++j) {
      float u1 = bx[j][0], v1 = bx[j][1], u2 = bx[j][2], v2 = bx[j][3];
      float aj = (u2 - u1) * (v2 - v1);
      float iw = fminf(x2, u2) - fmaxf(x1, u1); iw = fmaxf(iw, 0.f);
      float ih = fminf(y2, v2) - fmaxf(y1, v1); ih = fmaxf(ih, 0.f);
      float inter = iw * ih;
      float iou = inter / (ai + aj - inter + 1e-9f);
      if (iou > 0.7f) accm |= (1ull << (j & 63));
    }
  }
  maskw[((size_t)n * 1024 + t) * 16 + c] = accm;
}

// ---- serial greedy scan (reg-prefetch from global) + stable partition ----
__global__ __launch_bounds__(64) void finalk(const u64* __restrict__ maskw,
                                             const float* __restrict__ scs,
                                             const float* __restrict__ tb,
                                             float* __restrict__ out) {
  int n = blockIdx.x;
  int lane = threadIdx.x;
  __shared__ float lsc[1024];
  __shared__ unsigned short ordA[1024];
  __shared__ unsigned short ordB[1024];
  for (int e = lane; e < 1024; e += 64)
    lsc[e] = (e < PRE_K) ? scs[n * PRE_K + e] : -__builtin_inff();
  __syncthreads();

  // fold validity into initial suppression mask: lane c (<16) owns word c
  u64 sup = 0;
#pragma unroll
  for (int c = 0; c < 16; ++c) {
    u64 b = __ballot(!(lsc[c * 64 + lane] > -__builtin_inff()));
    if (lane == c) sup = b;
  }

  const u64* gm = maskw + (size_t)n * 1024 * 16;
  u64 pre[16];
#pragma unroll
  for (int d = 0; d < 16; ++d)
    pre[d] = (lane < 16) ? gm[d * 16 + lane] : 0ull;

  // serial greedy scan: no memory op on the dependency chain
  for (int i0 = 0; i0 < 1024; i0 += 16) {
#pragma unroll
    for (int d = 0; d < 16; ++d) {
      int i = i0 + d;
      u64 mi = pre[d];
      int nx = i + 16;
      pre[d] = (nx < 1024 && lane < 16) ? gm[(size_t)nx * 16 + lane] : 0ull;
      int w = i >> 6;
      u64 sw = shfl64(sup, w);
      bool supbit = (sw >> (i & 63)) & 1ull;
      if (!supbit) sup |= mi;
    }
  }

  // stable partition: survivors (rank order) then rest (index order)
  u64 ltm = (1ull << lane) - 1ull;
  u32 baseA = 0, baseB = 0;
  for (int c = 0; c < 16; ++c) {
    int i = c * 64 + lane;
    u64 sw = shfl64(sup, c);
    bool bit = (sw >> lane) & 1ull;
    bool vi = i < PRE_K;
    bool sf = vi && !bit && (lsc[vi ? i : 0] > -__builtin_inff());
    u64 mA = __ballot(sf);
    u64 mB = __ballot(vi && !sf);
    if (sf) ordA[baseA + __popcll(mA & ltm)] = (unsigned short)i;
    else if (vi) ordB[baseB + __popcll(mB & ltm)] = (unsigned short)i;
    baseA += (u32)__popcll(mA);
    baseB += (u32)__popcll(mB);
  }
  __syncthreads();

  for (int r = 0; r < 4; ++r) {
    int k = r * 64 + lane;   // 0..255
    int fi; float v;
    if (k < (int)baseA) { fi = ordA[k]; v = lsc[fi]; }
    else { fi = ordB[k - baseA]; v = -__builtin_inff(); }
    const float* bp = tb + ((size_t)n * PRE_K + fi) * 4;
    float* kb = out + KB_OFF + ((size_t)n * 256 + k) * 4;
    kb[0] = bp[0]; kb[1] = bp[1]; kb[2] = bp[2]; kb[3] = bp[3];
    out[KS_OFF + (size_t)n * 256 + k] = v;
  }
}

extern "C" void kernel_launch(void* const* d_in, const int* in_sizes, int n_in,
                              void* d_out, int out_size, void* d_ws, size_t ws_size,
                              hipStream_t stream) {
  const float* x     = (const float*)d_in[0];
  const float* wc    = (const float*)d_in[1];
  const float* bconv = (const float*)d_in[2];
  const float* woff  = (const float*)d_in[3];
  const float* boff  = (const float*)d_in[4];
  const float* wlog  = (const float*)d_in[5];
  const float* blog  = (const float*)d_in[6];
  const int* ihp     = (const int*)d_in[7];
  const int* iwp     = (const int*)d_in[8];
  float* out = (float*)d_out;
  char* ws = (char*)d_ws;

  float* wt   = (float*)(ws + WT_OFF);
  u32* hist   = (u32*)(ws + HIST_OFF);
  u32* cnt    = (u32*)(ws + CNT_OFF);
  u32* cut    = (u32*)(ws + CUT_OFF);
  u64* cand   = (u64*)(ws + CAND_OFF);
  float* tb   = (float*)(ws + TB_OFF);
  float* scs  = (float*)(ws + SCS_OFF);
  u64* maskw  = (u64*)(ws + MASK_OFF);
  float* scarr = (ws_size >= WS_NEED) ? (float*)(ws + SCARR_OFF) : nullptr;

  hipMemsetAsync(ws + HIST_OFF, 0, (CAND_OFF - HIST_OFF), stream);
  hipLaunchKernelGGL(wtransk, dim3(576), dim3(256), 0, stream, wc, wt);
  hipLaunchKernelGGL(convk, dim3(32, 16, 2), dim3(256), 0, stream,
                     x, wt, bconv, woff, boff, wlog, blog, ihp, iwp, out, hist, scarr);
  hipLaunchKernelGGL(cutoffk, dim3(2), dim3(256), 0, stream, hist, cut);
  hipLaunchKernelGGL(collectk, dim3(512), dim3(256), 0, stream, out, scarr, cut, cnt, cand);
  hipLaunchKernelGGL(ranksel, dim3(2), dim3(1024), 0, stream, cand, cnt, out, tb, scs);
  hipLaunchKernelGGL(maskk, dim3(16, 2), dim3(1024), 0, stream, tb, maskw);
  hipLaunchKernelGGL(finalk, dim3(2), dim3(64), 0, stream, maskw, scs, tb, out);
}

// Round 5
// 629.890 us; speedup vs baseline: 1.6611x; 1.3064x over previous
//
#include <hip/hip_runtime.h>
#include <stdint.h>

typedef unsigned int u32;
typedef unsigned long long u64;
typedef __attribute__((ext_vector_type(8))) short short8;
typedef __attribute__((ext_vector_type(16))) float f32x16;

#define DEVI __device__ __forceinline__

constexpr int PRE_K = 1000;
constexpr int CAP = 8192;

// workspace layout (bytes)
constexpr size_t WF_OFF    = 0;         // frag-swizzled split weights: 3*4*72*1024 = 884736
constexpr size_t HIST_OFF  = 884736;    // 2*4096 u32 = 32768
constexpr size_t CNT_OFF   = 917504;    // 2 u32 (+pad)
constexpr size_t CUT_OFF   = 917568;    // 2 u32 (+pad)
constexpr size_t CAND_OFF  = 917632;    // 2*8192 u64 = 131072 -> 1048704
constexpr size_t TB_OFF    = 1048704;   // 2*1000*4 f32 = 32000 -> 1080704
constexpr size_t SCS_OFF   = 1080704;   // 2*1000 f32 = 8000 -> 1088704
constexpr size_t MASK_OFF  = 1088768;   // 2*1024*16 u64 = 262144 -> 1350912
constexpr size_t SCARR_OFF = 1350912;   // 2*65536 f32 = 524288 -> 1875200
constexpr size_t WS_NEED   = 1875200;

constexpr size_t KB_OFF = 655360;   // kept_boxes offset in d_out (floats)
constexpr size_t KS_OFF = 657408;   // kept_scores offset in d_out (floats)

DEVI u32 fkey(float f) {
  u32 u = __float_as_uint(f);
  return (u & 0x80000000u) ? ~u : (u | 0x80000000u);
}

DEVI u64 shfl64(u64 v, int src) {
  int lo = __shfl((int)(u32)v, src, 64);
  int hi = __shfl((int)(u32)(v >> 32), src, 64);
  return ((u64)(u32)hi << 32) | (u64)(u32)lo;
}

// RNE f32 -> bf16 bits
DEVI u32 rne16(u32 u) { return (u + 0x7FFFu + ((u >> 16) & 1u)) >> 16; }

// ---- W_conv (co,ci,3,3) -> frag-order split-bf16 weights ----
// k = tap*128 + ci ; frag_id = (s*4 + (co>>5))*72 + (k>>4) ; slot = ((k>>3)&1)*32 + (co&31)
__global__ void wsplitk(const float* __restrict__ wc, float* __restrict__ wf) {
  int j = blockIdx.x * 256 + threadIdx.x;
  if (j >= 18432) return;
  int co = j / 144;
  int koct = j % 144;          // 8-element k group
  short8 h8, m8, l8;
#pragma unroll
  for (int jj = 0; jj < 8; ++jj) {
    int kk = koct * 8 + jj;
    int tap = kk >> 7, ci = kk & 127;
    float v = wc[(co * 128 + ci) * 9 + tap];
    u32 u0 = __float_as_uint(v);
    u32 hb = rne16(u0);
    float r1 = v - __uint_as_float(hb << 16);
    u32 u1 = __float_as_uint(r1);
    u32 mb = rne16(u1);
    float r2 = r1 - __uint_as_float(mb << 16);
    u32 lb = rne16(__float_as_uint(r2));
    h8[jj] = (short)hb; m8[jj] = (short)mb; l8[jj] = (short)lb;
  }
  int slot = ((koct & 1) << 5) + (co & 31);
  int kg = koct >> 1;
  int cblk = co >> 5;
  char* base = (char*)wf;
  *(short8*)(base + ((size_t)((0 * 4 + cblk) * 72 + kg) * 64 + slot) * 16) = h8;
  *(short8*)(base + ((size_t)((1 * 4 + cblk) * 72 + kg) * 64 + slot) * 16) = m8;
  *(short8*)(base + ((size_t)((2 * 4 + cblk) * 72 + kg) * 64 + slot) * 16) = l8;
}

// ---- fused split-bf16 MFMA conv3x3 + bias + relu + heads + decode + hist ----
__global__ __launch_bounds__(256, 2) void convk(
    const float* __restrict__ x, const float* __restrict__ wf,
    const float* __restrict__ bconv,
    const float* __restrict__ woff, const float* __restrict__ boff,
    const float* __restrict__ wlog, const float* __restrict__ blog,
    const int* __restrict__ ihp, const int* __restrict__ iwp,
    float* __restrict__ out, u32* __restrict__ hist, float* __restrict__ scarr)
{
  __shared__ union {
    float halo[10][18][36];    // [hh][ww][ci] fp32, pad 36
    float tch[2][32][132];     // epilogue t chunks [slot][px][co pad]
  } sm;

  const int tid = threadIdx.x;
  const int l = tid & 63, wv = tid >> 6;
  const int mhalf = wv >> 1, nhalf = wv & 1;
  const int lm = l & 31, lg = l >> 5;
  const int bx = blockIdx.x, by = blockIdx.y, n = blockIdx.z;

  f32x16 acc[2][2];
#pragma unroll
  for (int mi = 0; mi < 2; ++mi)
#pragma unroll
    for (int ni = 0; ni < 2; ++ni)
#pragma unroll
      for (int q = 0; q < 16; ++q) acc[mi][ni][q] = 0.f;

#pragma unroll 1
  for (int cb = 0; cb < 4; ++cb) {
    __syncthreads();
    // stage fp32 halo: 32 ci x 10 h x 18 w
    for (int e = tid; e < 5760; e += 256) {
      int ci = e / 180, rem = e % 180;
      int hh = rem / 18, ww = rem % 18;
      int gh = by * 8 + hh - 1, gw = bx * 16 + ww - 1;
      float v = 0.f;
      if ((unsigned)gh < 256u && (unsigned)gw < 256u)
        v = x[(((size_t)n * 128 + cb * 32 + ci) * 256 + gh) * 256 + gw];
      sm.halo[hh][ww][ci] = v;
    }
    __syncthreads();

#pragma unroll 1
    for (int tap = 0; tap < 9; ++tap) {
      int dy = tap / 3 - 1, dx = tap % 3 - 1;
      // A fragments (split-3) from halo
      short8 Af[3][2][2];
#pragma unroll
      for (int mi = 0; mi < 2; ++mi) {
        int hh = mhalf * 4 + mi * 2 + (lm >> 4) + dy + 1;
        int ww = (lm & 15) + dx + 1;
#pragma unroll
        for (int ks = 0; ks < 2; ++ks) {
          const float* ap = &sm.halo[hh][ww][ks * 16 + lg * 8];
          float4 va = *(const float4*)ap;
          float4 vb = *(const float4*)(ap + 4);
          float fv[8] = {va.x, va.y, va.z, va.w, vb.x, vb.y, vb.z, vb.w};
          short8 ah, am, al;
#pragma unroll
          for (int jj = 0; jj < 8; ++jj) {
            u32 u0 = __float_as_uint(fv[jj]);
            u32 hb = rne16(u0);
            float r1 = fv[jj] - __uint_as_float(hb << 16);
            u32 u1 = __float_as_uint(r1);
            u32 mb = rne16(u1);
            float r2 = r1 - __uint_as_float(mb << 16);
            u32 lb = rne16(__float_as_uint(r2));
            ah[jj] = (short)hb; am[jj] = (short)mb; al[jj] = (short)lb;
          }
          Af[0][mi][ks] = ah; Af[1][mi][ks] = am; Af[2][mi][ks] = al;
        }
      }
      // B fragments direct from frag-ordered global weights; 6 split products
      const char* wfb = (const char*)wf;
#pragma unroll
      for (int sb = 0; sb < 3; ++sb) {
        short8 Bf[2][2];
#pragma unroll
        for (int ni = 0; ni < 2; ++ni)
#pragma unroll
          for (int ks = 0; ks < 2; ++ks) {
            int fid = (sb * 4 + nhalf * 2 + ni) * 72 + tap * 8 + cb * 2 + ks;
            Bf[ni][ks] = *(const short8*)(wfb + ((size_t)fid * 64 + l) * 16);
          }
#pragma unroll
        for (int sa = 0; sa < 3 - sb; ++sa)
#pragma unroll
          for (int mi = 0; mi < 2; ++mi)
#pragma unroll
            for (int ni = 0; ni < 2; ++ni)
#pragma unroll
              for (int ks = 0; ks < 2; ++ks)
                acc[mi][ni] = __builtin_amdgcn_mfma_f32_32x32x16_bf16(
                    Af[sa][mi][ks], Bf[ni][ks], acc[mi][ni], 0, 0, 0);
      }
    }
  }

  // ---- epilogue: bias+relu -> LDS t chunks -> heads -> decode ----
  __syncthreads();
  const int ihv = ihp[0], iwv = iwp[0];
  float bcv[2];
  bcv[0] = bconv[nhalf * 64 + lm];
  bcv[1] = bconv[nhalf * 64 + 32 + lm];
  const int cq = l >> 4;
  const int pxl = (nhalf << 4) + (l & 15);
  const float scale = (float)iwv / 256.0f;

#pragma unroll
  for (int r = 0; r < 2; ++r) {
    if (r) __syncthreads();
#pragma unroll
    for (int ni = 0; ni < 2; ++ni)
#pragma unroll
      for (int rg = 0; rg < 16; ++rg) {
        int row = (rg & 3) + ((rg >> 2) << 3) + ((l >> 5) << 2);
        sm.tch[mhalf][row][(nhalf << 6) + (ni << 5) + lm] =
            fmaxf(acc[r][ni][rg] + bcv[ni], 0.f);
      }
    __syncthreads();

    float tv[32];
#pragma unroll
    for (int i = 0; i < 8; ++i) {
      float4 t4 = *(const float4*)&sm.tch[mhalf][pxl][(cq << 5) + (i << 2)];
      tv[i * 4 + 0] = t4.x; tv[i * 4 + 1] = t4.y;
      tv[i * 4 + 2] = t4.z; tv[i * 4 + 3] = t4.w;
    }
    float s19[19];
#pragma unroll
    for (int o = 0; o < 19; ++o) {
      const float* wh = (o < 18) ? (woff + o * 128) : wlog;
      const float4* w4 = (const float4*)(wh + (cq << 5));
      float a0 = 0.f;
#pragma unroll
      for (int i = 0; i < 8; ++i) {
        float4 wv4 = w4[i];
        a0 = fmaf(tv[i * 4 + 0], wv4.x, a0);
        a0 = fmaf(tv[i * 4 + 1], wv4.y, a0);
        a0 = fmaf(tv[i * 4 + 2], wv4.z, a0);
        a0 = fmaf(tv[i * 4 + 3], wv4.w, a0);
      }
      s19[o] = a0;
    }
#pragma unroll
    for (int o = 0; o < 19; ++o) {
      s19[o] += __shfl_xor(s19[o], 16, 64);
      s19[o] += __shfl_xor(s19[o], 32, 64);
    }
    if (cq == 0) {
      int bpx = (mhalf << 6) + (r << 5) + pxl;
      int ph = bpx >> 4, pw = bpx & 15;
      int gh = by * 8 + ph, gw = bx * 16 + pw;
      float sc = s19[18] + blog[0];
      // xs_lin uses linspace(0,image_h-1,Wf) indexed by w; ys_lin uses image_w, indexed by h
      float xv = (float)((double)gw * ((double)(ihv - 1) / 255.0));
      float yv = (float)((double)gh * ((double)(iwv - 1) / 255.0));
      float mnx = __builtin_inff(), mny = __builtin_inff();
      float mxx = -__builtin_inff(), mxy = -__builtin_inff();
#pragma unroll
      for (int p = 0; p < 9; ++p) {
        float ox = expf((s19[2 * p] + boff[2 * p]) * scale) - 1.f + xv;
        float oy = expf((s19[2 * p + 1] + boff[2 * p + 1]) * scale) - 1.f + yv;
        float cx2 = fminf(fmaxf(ox, 0.f), (float)(iwv - 1));
        float cy2 = fminf(fmaxf(oy, 0.f), (float)(ihv - 1));
        mnx = fminf(mnx, cx2); mxx = fmaxf(mxx, cx2);
        mny = fminf(mny, cy2); mxy = fmaxf(mxy, cy2);
      }
      size_t pix = (size_t)n * 65536 + (size_t)gh * 256 + gw;
      float* rec = out + pix * 5;
      rec[0] = sc; rec[1] = mnx; rec[2] = mny; rec[3] = mxx; rec[4] = mxy;
      if (scarr) scarr[pix] = sc;
      atomicAdd(&hist[n * 4096 + (fkey(sc) >> 20)], 1u);
    }
  }
}

// ---- find cutoff bin (rank PRE_K) ----
__global__ __launch_bounds__(256) void cutoffk(const u32* __restrict__ hist, u32* __restrict__ cut) {
  int n = blockIdx.x;
  const u32* h = hist + n * 4096;
  __shared__ u32 pre[256];
  int t = threadIdx.x;
  u32 s0 = 0;
  for (int k = 0; k < 16; ++k) s0 += h[4095 - (t * 16 + k)];
  pre[t] = s0;
  __syncthreads();
  for (int off = 1; off < 256; off <<= 1) {
    u32 add = (t >= off) ? pre[t - off] : 0u;
    __syncthreads();
    pre[t] += add;
    __syncthreads();
  }
  u32 incl = pre[t];
  u32 excl = incl - s0;
  if (incl >= (u32)PRE_K && excl < (u32)PRE_K) {
    u32 cum = excl;
    for (int k = 0; k < 16; ++k) {
      int b = 4095 - (t * 16 + k);
      cum += h[b];
      if (cum >= (u32)PRE_K) { cut[n] = ((u32)b) << 20; break; }
    }
  }
}

// ---- collect candidates >= cutoff ----
__global__ void collectk(const float* __restrict__ out, const float* __restrict__ scarr,
                         const u32* __restrict__ cut,
                         u32* __restrict__ cnt, u64* __restrict__ cand) {
  int e = blockIdx.x * 256 + threadIdx.x;
  int n = e >> 16;
  u32 pix = e & 65535;
  float sc = scarr ? scarr[e] : out[((size_t)n * 65536 + pix) * 5];
  u32 key = fkey(sc);
  if (key >= cut[n]) {
    u32 pos = atomicAdd(&cnt[n], 1u);
    if (pos < (u32)CAP)
      cand[(size_t)n * CAP + pos] = ((u64)key << 32) | (u64)(0xFFFFFFFFu - pix);
  }
}

// ---- O(m^2) rank selection of top-1000 (order-invariant, exact ties by idx) ----
__global__ __launch_bounds__(1024) void ranksel(const u64* __restrict__ cand, const u32* __restrict__ cnt,
                                                const float* __restrict__ out,
                                                float* __restrict__ tb, float* __restrict__ scs) {
  int n = blockIdx.x;
  int t = threadIdx.x;
  __shared__ u64 d[CAP];
  u32 m = cnt[n]; if (m > (u32)CAP) m = CAP;
  for (int i = t; i < (int)m; i += 1024) d[i] = cand[(size_t)n * CAP + i];
  __syncthreads();
  for (int i = t; i < (int)m; i += 1024) {
    u64 ki = d[i];
    u32 r = 0;
    for (u32 j = 0; j < m; ++j) r += (d[j] > ki) ? 1u : 0u;
    if (r < (u32)PRE_K) {
      u32 pix = 0xFFFFFFFFu - (u32)(ki & 0xFFFFFFFFull);
      const float* rec = out + ((size_t)n * 65536 + pix) * 5;
      float sc = rec[0];
      float b0 = rec[1], b1 = rec[2], b2 = rec[3], b3 = rec[4];
      bool valid = ((b2 - b0) >= 0.f) && ((b3 - b1) >= 0.f);
      scs[n * PRE_K + r] = valid ? sc : -__builtin_inff();
      float* tbp = tb + ((size_t)n * PRE_K + r) * 4;
      tbp[0] = b0; tbp[1] = b1; tbp[2] = b2; tbp[3] = b3;
    }
  }
}

// ---- pairwise IoU suppression bitmasks; grid (colchunk=16, n=2) ----
__global__ __launch_bounds__(1024) void maskk(const float* __restrict__ tb, u64* __restrict__ maskw) {
  int c = blockIdx.x;
  int n = blockIdx.y;
  int t = threadIdx.x;
  __shared__ float bx[PRE_K][4];
  for (int e = t; e < PRE_K * 4; e += 1024) ((float*)bx)[e] = tb[(size_t)n * PRE_K * 4 + e];
  __syncthreads();
  u64 accm = 0;
  if (t < PRE_K) {
    float x1 = bx[t][0], y1 = bx[t][1], x2 = bx[t][2], y2 = bx[t][3];
    float ai = (x2 - x1) * (y2 - y1);
    int j0 = max(t + 1, c * 64), j1 = min(PRE_K, c * 64 + 64);
    for (int j = j0; j < j1; ++j) {
      float u1 = bx[j][0], v1 = bx[j][1], u2 = bx[j][2], v2 = bx[j][3];
      float aj = (u2 - u1) * (v2 - v1);
      float iw = fminf(x2, u2) - fmaxf(x1, u1); iw = fmaxf(iw, 0.f);
      float ih = fminf(y2, v2) - fmaxf(y1, v1); ih = fmaxf(ih, 0.f);
      float inter = iw * ih;
      float iou = inter / (ai + aj - inter + 1e-9f);
      if (iou > 0.7f) accm |= (1ull << (j & 63));
    }
  }
  maskw[((size_t)n * 1024 + t) * 16 + c] = accm;
}

// ---- serial greedy scan (reg-prefetch from global) + stable partition ----
__global__ __launch_bounds__(64) void finalk(const u64* __restrict__ maskw,
                                             const float* __restrict__ scs,
                                             const float* __restrict__ tb,
                                             float* __restrict__ out) {
  int n = blockIdx.x;
  int lane = threadIdx.x;
  __shared__ float lsc[1024];
  __shared__ unsigned short ordA[1024];
  __shared__ unsigned short ordB[1024];
  for (int e = lane; e < 1024; e += 64)
    lsc[e] = (e < PRE_K) ? scs[n * PRE_K + e] : -__builtin_inff();
  __syncthreads();

  u64 sup = 0;
#pragma unroll
  for (int c = 0; c < 16; ++c) {
    u64 b = __ballot(!(lsc[c * 64 + lane] > -__builtin_inff()));
    if (lane == c) sup = b;
  }

  const u64* gm = maskw + (size_t)n * 1024 * 16;
  u64 pre[16];
#pragma unroll
  for (int d = 0; d < 16; ++d)
    pre[d] = (lane < 16) ? gm[d * 16 + lane] : 0ull;

  for (int i0 = 0; i0 < 1024; i0 += 16) {
#pragma unroll
    for (int d = 0; d < 16; ++d) {
      int i = i0 + d;
      u64 mi = pre[d];
      int nx = i + 16;
      pre[d] = (nx < 1024 && lane < 16) ? gm[(size_t)nx * 16 + lane] : 0ull;
      int w = i >> 6;
      u64 sw = shfl64(sup, w);
      bool supbit = (sw >> (i & 63)) & 1ull;
      if (!supbit) sup |= mi;
    }
  }

  u64 ltm = (1ull << lane) - 1ull;
  u32 baseA = 0, baseB = 0;
  for (int c = 0; c < 16; ++c) {
    int i = c * 64 + lane;
    u64 sw = shfl64(sup, c);
    bool bit = (sw >> lane) & 1ull;
    bool vi = i < PRE_K;
    bool sf = vi && !bit && (lsc[vi ? i : 0] > -__builtin_inff());
    u64 mA = __ballot(sf);
    u64 mB = __ballot(vi && !sf);
    if (sf) ordA[baseA + __popcll(mA & ltm)] = (unsigned short)i;
    else if (vi) ordB[baseB + __popcll(mB & ltm)] = (unsigned short)i;
    baseA += (u32)__popcll(mA);
    baseB += (u32)__popcll(mB);
  }
  __syncthreads();

  for (int r = 0; r < 4; ++r) {
    int k = r * 64 + lane;
    int fi; float v;
    if (k < (int)baseA) { fi = ordA[k]; v = lsc[fi]; }
    else { fi = ordB[k - baseA]; v = -__builtin_inff(); }
    const float* bp = tb + ((size_t)n * PRE_K + fi) * 4;
    float* kb = out + KB_OFF + ((size_t)n * 256 + k) * 4;
    kb[0] = bp[0]; kb[1] = bp[1]; kb[2] = bp[2]; kb[3] = bp[3];
    out[KS_OFF + (size_t)n * 256 + k] = v;
  }
}

extern "C" void kernel_launch(void* const* d_in, const int* in_sizes, int n_in,
                              void* d_out, int out_size, void* d_ws, size_t ws_size,
                              hipStream_t stream) {
  const float* x     = (const float*)d_in[0];
  const float* wc    = (const float*)d_in[1];
  const float* bconv = (const float*)d_in[2];
  const float* woff  = (const float*)d_in[3];
  const float* boff  = (const float*)d_in[4];
  const float* wlog  = (const float*)d_in[5];
  const float* blog  = (const float*)d_in[6];
  const int* ihp     = (const int*)d_in[7];
  const int* iwp     = (const int*)d_in[8];
  float* out = (float*)d_out;
  char* ws = (char*)d_ws;

  float* wf   = (float*)(ws + WF_OFF);
  u32* hist   = (u32*)(ws + HIST_OFF);
  u32* cnt    = (u32*)(ws + CNT_OFF);
  u32* cut    = (u32*)(ws + CUT_OFF);
  u64* cand   = (u64*)(ws + CAND_OFF);
  float* tb   = (float*)(ws + TB_OFF);
  float* scs  = (float*)(ws + SCS_OFF);
  u64* maskw  = (u64*)(ws + MASK_OFF);
  float* scarr = (ws_size >= WS_NEED) ? (float*)(ws + SCARR_OFF) : nullptr;

  hipMemsetAsync(ws + HIST_OFF, 0, (CAND_OFF - HIST_OFF), stream);
  hipLaunchKernelGGL(wsplitk, dim3(72), dim3(256), 0, stream, wc, wf);
  hipLaunchKernelGGL(convk, dim3(16, 32, 2), dim3(256), 0, stream,
                     x, wf, bconv, woff, boff, wlog, blog, ihp, iwp, out, hist, scarr);
  hipLaunchKernelGGL(cutoffk, dim3(2), dim3(256), 0, stream, hist, cut);
  hipLaunchKernelGGL(collectk, dim3(512), dim3(256), 0, stream, out, scarr, cut, cnt, cand);
  hipLaunchKernelGGL(ranksel, dim3(2), dim3(1024), 0, stream, cand, cnt, out, tb, scs);
  hipLaunchKernelGGL(maskk, dim3(16, 2), dim3(1024), 0, stream, tb, maskw);
  hipLaunchKernelGGL(finalk, dim3(2), dim3(64), 0, stream, maskw, scs, tb, out);
}